// Round 19
// baseline (238.912 us; speedup 1.0000x reference)
//
#include <hip/hip_runtime.h>

// VQ-VAE VectorQuantizer forward, fp32, MI355X.
// B=64, C=D=64, H=W=32 -> N=65536 pixels, K=1024 codes.
// Outputs (flat concat): [0] loss, [1..4194305) quantized BCHW, [4194305..) indices (as float)
//
// R19: epilogue-VALU attack + launch-count cut.
// R17/R18 null A/B: geometry changes didn't move gemm (44us) -> binding cost is
// the per-score TOP2 VALU (7 ops/score, ~40k cyc/SIMD > MFMA 30k) + serial
// phases. Now: (a) single 6-deep MFMA chain/tile (acc chaining free, no adds),
// (b) 4-tile barrier windows + 4-score median-tree top2 (~4.5 ops/score),
// strict-< tie-breaks toward lower k == first-occurrence. Barriers 64->16.
// (c) loss fused into gather: u64 fixed-point atomicAdd (deterministic) +
// last-block finalize. 4 kernels total.
// MARGIN 8e-5 (R14-18 validated). Exact-path arithmetic BIT-IDENTICAL to
// R0-R18 (passed): pairwise-8 x_sq (contract off), d-ascending fp32 FMA
// chain, (xsq-2d)+esq, first-occurrence argmin.

#define KCODES 1024
#define DDIM   64
#define NPIX   65536
#define QELEMS 4194304
#define IDX_OFF (1 + QELEMS)
#define MARGIN 8e-5f
#define WT     4           // tiles per window
#define NWIN   16          // 64 tiles / 4
#define NB     8           // pixels per cleanup chunk

typedef __attribute__((ext_vector_type(8))) short bf16x8;
typedef __attribute__((ext_vector_type(4))) float f32x4;

static __device__ __forceinline__ unsigned short f2bf(float f) {
    unsigned int u = __float_as_uint(f);
    unsigned int r = (u + 0x7FFFu + ((u >> 16) & 1u)) >> 16;   // RNE
    return (unsigned short)r;
}
static __device__ __forceinline__ float bf2f(unsigned short h) {
    return __uint_as_float(((unsigned int)h) << 16);
}

// ---------------- e prep: esq (EXACT pairwise-8) + bf16 split of (-2e) + zero ctrs ----------------
__global__ void __launch_bounds__(256) esplit_kernel(const float* __restrict__ e,
                                                     float* __restrict__ esq,
                                                     unsigned short* __restrict__ Eh,
                                                     unsigned short* __restrict__ El,
                                                     int* __restrict__ count,
                                                     unsigned long long* __restrict__ lsum,
                                                     int* __restrict__ ldone) {
    if (blockIdx.x == 0 && threadIdx.x == 0) { *count = 0; *lsum = 0ULL; *ldone = 0; }
    int k = blockIdx.x * 256 + threadIdx.x;
    if (k >= KCODES) return;
    const float* row = e + k * DDIM;
    {
#pragma clang fp contract(off)
        float r[8];
#pragma unroll
        for (int j = 0; j < 8; ++j) r[j] = row[j] * row[j];
#pragma unroll
        for (int i = 1; i < 8; ++i) {
#pragma unroll
            for (int j = 0; j < 8; ++j) { float v = row[i * 8 + j]; r[j] += v * v; }
        }
        esq[k] = ((r[0] + r[1]) + (r[2] + r[3])) + ((r[4] + r[5]) + (r[6] + r[7]));
    }
#pragma unroll
    for (int d = 0; d < DDIM; ++d) {
        float v = -2.0f * row[d];              // exact scaling
        unsigned short h = f2bf(v);
        Eh[k * DDIM + d] = h;
        El[k * DDIM + d] = f2bf(v - bf2f(h));
    }
}

// ---------------- MFMA approx scores + top-2 + fused compact ----------------
// Block = 256 thr = 4 waves; 64 px/block. 4-tile windows, 16 barriers.
__global__ void __launch_bounds__(256, 4) gemm_kernel(const float* __restrict__ x,
                                                      const unsigned short* __restrict__ Eh,
                                                      const unsigned short* __restrict__ El,
                                                      const float* __restrict__ esq,
                                                      int* __restrict__ count,
                                                      int* __restrict__ list,
                                                      int* __restrict__ idx,
                                                      float* __restrict__ out) {
    __shared__ float x_lds[DDIM][64];              // 16KB
    __shared__ float esq_lds[KCODES];              // 4KB
    __shared__ unsigned char btile[2][WT][4096];   // 32KB dbuf window (per tile: Eh 2KB | El 2KB)
    __shared__ int sflag[64];

    const int tid = threadIdx.x;
    const int w = __builtin_amdgcn_readfirstlane(tid >> 6);
    const int l = tid & 63;
    const int g = l >> 4;              // 0..3
    const int col = l & 15;
    const int pxbase = blockIdx.x * 64;
    const int b = pxbase >> 10;
    const int p0 = pxbase & 1023;

    // stage x tile + esq
    {
        const float* xg = x + (size_t)b * 65536 + p0;
        for (int t = tid; t < DDIM * 64; t += 256)
            x_lds[t >> 6][t & 63] = xg[(size_t)(t >> 6) * 1024 + (t & 63)];
        for (int t = tid; t < KCODES; t += 256)
            esq_lds[t] = esq[t];
    }
    __syncthreads();

    // A fragments: row = col (px_local = w*16+col), k(d)-slot = g*8 + j (+32 per d-half)
    bf16x8 Ah0, Ah1, Al0, Al1;
    {
        const int pxl = w * 16 + col;
#pragma unroll
        for (int j = 0; j < 8; ++j) {
            float v0 = x_lds[g * 8 + j][pxl];
            unsigned short h0 = f2bf(v0);
            Ah0[j] = (short)h0;
            Al0[j] = (short)f2bf(v0 - bf2f(h0));
            float v1 = x_lds[32 + g * 8 + j][pxl];
            unsigned short h1 = f2bf(v1);
            Ah1[j] = (short)h1;
            Al1[j] = (short)f2bf(v1 - bf2f(h1));
        }
    }

    // B staging: thread covers 16B of each 4KB tile; 4 tiles per window.
    // swizzle: dchunk ^= (code&7)<<4 (bijective within each 128B code-row).
    const unsigned short* src_base = (tid < 128) ? Eh : El;
    const int u = tid & 127;
    const int code_w = u >> 3;
    const int dst_off = ((tid >> 7) << 11) + (code_w << 7)
                      + (((u & 7) << 4) ^ ((code_w & 7) << 4));
    float4 s0g, s1g, s2g, s3g;
    auto LDW = [&](int i) {    // load window i (tiles 4i..4i+3)
        const char* sb = (const char*)src_base + (size_t)(4 * i) * 2048 + (size_t)u * 16;
        s0g = *(const float4*)(sb);
        s1g = *(const float4*)(sb + 2048);
        s2g = *(const float4*)(sb + 4096);
        s3g = *(const float4*)(sb + 6144);
    };
    auto STW = [&](int i) {
        *(float4*)&btile[i & 1][0][dst_off] = s0g;
        *(float4*)&btile[i & 1][1][dst_off] = s1g;
        *(float4*)&btile[i & 1][2][dst_off] = s2g;
        *(float4*)&btile[i & 1][3][dst_off] = s3g;
    };

    const int cx = (col & 7) << 4;
    const int rb = col << 7;
    const int oh0 = rb + ((g << 4) ^ cx);
    const int oh1 = rb + (((g << 4) + 64) ^ cx);

    float m1_0 = 3.4e38f, m1_1 = 3.4e38f, m1_2 = 3.4e38f, m1_3 = 3.4e38f;
    float m2_0 = 3.4e38f, m2_1 = 3.4e38f, m2_2 = 3.4e38f, m2_3 = 3.4e38f;
    int i1_0 = 0, i1_1 = 0, i1_2 = 0, i1_3 = 0;

    LDW(0); STW(0);    // window 0 staged (vmcnt auto before ds_write)
    LDW(1);            // window 1 in flight
    __syncthreads();

#pragma unroll 1
    for (int wn = 0; wn < NWIN; ++wn) {
        if (wn + 1 < NWIN) STW(wn + 1);   // buf (wn+1)&1: read finished at last barrier
        if (wn + 2 < NWIN) LDW(wn + 2);

        const unsigned char* bw = &btile[wn & 1][0][0];
        const int kbase = wn * 64 + col;

        // 4 tiles, each a single 6-deep MFMA chain (3 split terms x 2 d-halves),
        // acc seeded with esq -> score = esq - 2*dot directly, zero VALU adds.
        f32x4 t0, t1, t2, t3;
#define CHAIN(J, ACC)                                                          \
        {                                                                      \
            const unsigned char* bp_ = bw + (J) * 4096;                        \
            const bf16x8 Bh0 = *(const bf16x8*)(bp_ + oh0);                    \
            const bf16x8 Bh1 = *(const bf16x8*)(bp_ + oh1);                    \
            const bf16x8 Bl0 = *(const bf16x8*)(bp_ + 2048 + oh0);             \
            const bf16x8 Bl1 = *(const bf16x8*)(bp_ + 2048 + oh1);             \
            const float qe_ = esq_lds[kbase + (J) * 16];                       \
            ACC = (f32x4){qe_, qe_, qe_, qe_};                                 \
            ACC = __builtin_amdgcn_mfma_f32_16x16x32_bf16(Ah0, Bh0, ACC, 0, 0, 0); \
            ACC = __builtin_amdgcn_mfma_f32_16x16x32_bf16(Al0, Bh0, ACC, 0, 0, 0); \
            ACC = __builtin_amdgcn_mfma_f32_16x16x32_bf16(Ah0, Bl0, ACC, 0, 0, 0); \
            ACC = __builtin_amdgcn_mfma_f32_16x16x32_bf16(Ah1, Bh1, ACC, 0, 0, 0); \
            ACC = __builtin_amdgcn_mfma_f32_16x16x32_bf16(Al1, Bh1, ACC, 0, 0, 0); \
            ACC = __builtin_amdgcn_mfma_f32_16x16x32_bf16(Ah1, Bl1, ACC, 0, 0, 0); \
        }
        CHAIN(0, t0)
        CHAIN(1, t1)
        CHAIN(2, t2)
        CHAIN(3, t3)
#undef CHAIN

        // 4-score median-tree top2 per pixel stream; ks ascending (kbase+16J);
        // all strict-< tie-breaks pick the lower k == first-occurrence.
#define WTOP(R, M1, M2, I1)                                                    \
        {                                                                      \
            float s0_ = t0[R], s1_ = t1[R], s2_ = t2[R], s3_ = t3[R];          \
            float p01 = fminf(s0_, s1_), q01 = fmaxf(s0_, s1_);                \
            float p23 = fminf(s2_, s3_), q23 = fmaxf(s2_, s3_);                \
            int i01 = (s1_ < s0_) ? kbase + 16 : kbase;                        \
            int i23 = (s3_ < s2_) ? kbase + 48 : kbase + 32;                   \
            float wmin = fminf(p01, p23);                                      \
            float wsec = fminf(fminf(q01, q23), fmaxf(p01, p23));              \
            int wi = (p23 < p01) ? i23 : i01;                                  \
            M2 = fminf(M2, fminf(wsec, fmaxf(M1, wmin)));                      \
            if (wmin < M1) I1 = wi;                                            \
            M1 = fminf(M1, wmin);                                              \
        }
        WTOP(0, m1_0, m2_0, i1_0)
        WTOP(1, m1_1, m2_1, i1_1)
        WTOP(2, m1_2, m2_2, i1_2)
        WTOP(3, m1_3, m2_3, i1_3)
#undef WTOP
        __syncthreads();
    }

    // cross-lane merge over the 16 lanes of group g; write idx/out + LDS flag
#define MERGE(M1, M2, I1, R)                                                   \
    {                                                                          \
        float a1_ = M1, a2_ = M2; int j1 = I1;                                 \
        _Pragma("unroll")                                                      \
        for (int off = 1; off < 16; off <<= 1) {                               \
            float b1 = __shfl_xor(a1_, off);                                   \
            int jb = __shfl_xor(j1, off);                                      \
            float b2 = __shfl_xor(a2_, off);                                   \
            float hi = fmaxf(a1_, b1);                                         \
            a2_ = fminf(fminf(a2_, b2), hi);                                   \
            if (b1 < a1_) j1 = jb;                                             \
            a1_ = fminf(a1_, b1);                                              \
        }                                                                      \
        if (col == 0) {                                                        \
            int pxl = w * 16 + g * 4 + (R);                                    \
            sflag[pxl] = (a2_ <= a1_ + MARGIN) ? 1 : 0;                        \
            int px = pxbase + pxl;                                             \
            idx[px] = j1;                                                      \
            out[IDX_OFF + px] = (float)j1;                                     \
        }                                                                      \
    }
    MERGE(m1_0, m2_0, i1_0, 0)
    MERGE(m1_1, m2_1, i1_1, 1)
    MERGE(m1_2, m2_2, i1_2, 2)
    MERGE(m1_3, m2_3, i1_3, 3)
#undef MERGE

    // fused compaction: wave 0 ballots the 64 flags, one atomicAdd
    __syncthreads();
    if (tid < 64) {
        const bool f = sflag[tid] != 0;
        unsigned long long m = __ballot(f);
        int base = 0;
        if (l == 0 && m) base = atomicAdd(count, __popcll(m));
        base = __shfl(base, 0);
        if (f) {
            unsigned long long below = m & ((1ULL << l) - 1ULL);
            list[base + __popcll(below)] = pxbase + tid;
        }
    }
}

// ---------------- cleanup (R17/R18-validated): exact argmin, e tiled via LDS ----------------
__global__ void __launch_bounds__(256, 4) cleanup_kernel(const float* __restrict__ x,
                                                         const float* __restrict__ e,
                                                         const float* __restrict__ esq,
                                                         const int* __restrict__ count,
                                                         const int* __restrict__ list,
                                                         int* __restrict__ idx,
                                                         float* __restrict__ out) {
    __shared__ float tile[DDIM][257];   // 65.8KB transpose tile
    __shared__ float xs[NB][68];
    __shared__ float xsqs[NB];
    __shared__ float rbest[4];
    __shared__ int   ridx[4];
    __shared__ int   plist[NB];

    const int tid = threadIdx.x;
    const int cnt = *count;
    const int nchunk = (cnt + NB - 1) / NB;

    for (int chunk = blockIdx.x; chunk < nchunk; chunk += gridDim.x) {
        const int base = chunk * NB;
        const int np = min(NB, cnt - base);      // block-uniform

        if (tid < np) plist[tid] = list[base + tid];
        __syncthreads();
        for (int q = tid; q < np * 64; q += 256) {
            const int pp = q >> 6, d = q & 63;
            const int p = plist[pp];
            xs[pp][d] = x[(size_t)(p >> 10) * 65536 + (size_t)d * 1024 + (p & 1023)];
        }
        __syncthreads();
        if (tid < np) {
#pragma clang fp contract(off)
            float r[8];
#pragma unroll
            for (int j = 0; j < 8; ++j) { float v = xs[tid][j]; r[j] = v * v; }
#pragma unroll
            for (int ii = 1; ii < 8; ++ii) {
#pragma unroll
                for (int j = 0; j < 8; ++j) { float v = xs[tid][ii * 8 + j]; r[j] += v * v; }
            }
            xsqs[tid] = ((r[0] + r[1]) + (r[2] + r[3])) + ((r[4] + r[5]) + (r[6] + r[7]));
        }

        float best[NB];
        int bidx[NB];
#pragma unroll
        for (int pp = 0; pp < NB; ++pp) { best[pp] = 3.4e38f; bidx[pp] = 0; }

#pragma unroll 1
        for (int T = 0; T < 4; ++T) {
            __syncthreads();
#pragma unroll
            for (int i = 0; i < 16; ++i) {
                const float4 v = *(const float4*)(e + (size_t)T * 16384 + (size_t)i * 1024 + tid * 4);
                const int c = 16 * i + (tid >> 4);
                const int d0 = (4 * tid) & 63;
                tile[d0 + 0][c] = v.x;
                tile[d0 + 1][c] = v.y;
                tile[d0 + 2][c] = v.z;
                tile[d0 + 3][c] = v.w;
            }
            __syncthreads();
            const float qe = esq[T * 256 + tid];
            const int kk = T * 256 + tid;
#pragma unroll
            for (int pp = 0; pp < NB; ++pp) {
                if (pp < np) {
                    float dt = 0.f;
#pragma unroll
                    for (int d = 0; d < DDIM; ++d)
                        dt = __builtin_fmaf(xs[pp][d], tile[d][tid], dt);
                    const float s = (xsqs[pp] - 2.0f * dt) + qe;
                    if (s < best[pp]) { best[pp] = s; bidx[pp] = kk; }
                }
            }
        }

#pragma unroll
        for (int pp = 0; pp < NB; ++pp) {
            if (pp < np) {
                float bb = best[pp];
                int bj = bidx[pp];
#pragma unroll
                for (int off = 1; off < 64; off <<= 1) {
                    float b2 = __shfl_xor(bb, off);
                    int k2 = __shfl_xor(bj, off);
                    if (b2 < bb || (b2 == bb && k2 < bj)) { bb = b2; bj = k2; }
                }
                if ((tid & 63) == 0) { rbest[tid >> 6] = bb; ridx[tid >> 6] = bj; }
                __syncthreads();
                if (tid == 0) {
                    float b0 = rbest[0]; int j0 = ridx[0];
#pragma unroll
                    for (int c2 = 1; c2 < 4; ++c2)
                        if (rbest[c2] < b0 || (rbest[c2] == b0 && ridx[c2] < j0)) {
                            b0 = rbest[c2]; j0 = ridx[c2];
                        }
                    const int p = plist[pp];
                    idx[p] = j0;
                    out[IDX_OFF + p] = (float)j0;
                }
                __syncthreads();
            }
        }
        __syncthreads();
    }
}

// ---------------- gather + fused deterministic loss (u64 fixed-point atomics) ----------------
__global__ void __launch_bounds__(256) gather_kernel(const float* __restrict__ x,
                                                     const float* __restrict__ e,
                                                     const int* __restrict__ idx,
                                                     float* __restrict__ out,
                                                     unsigned long long* __restrict__ lsum,
                                                     int* __restrict__ ldone) {
    const int bd = blockIdx.x;          // = b*64 + d
    const int b = bd >> 6;
    const int d = bd & 63;
    const size_t base = (size_t)bd * 1024;
    const int* idxb = idx + b * 1024;

    float acc = 0.f;
#pragma unroll
    for (int j = 0; j < 4; ++j) {
        int p = threadIdx.x + j * 256;
        int k = idxb[p];
        float ev = e[k * 64 + d];
        float xv = x[base + p];
        out[1 + base + p] = ev;         // quantized (straight-through == codebook value)
        float df = ev - xv;
        acc = __builtin_fmaf(df, df, acc);
    }
    __shared__ float sm[256];
    sm[threadIdx.x] = acc;
    __syncthreads();
    for (int s = 128; s > 0; s >>= 1) {
        if (threadIdx.x < s) sm[threadIdx.x] += sm[threadIdx.x + s];
        __syncthreads();
    }
    if (threadIdx.x == 0) {
        // fixed-point (x 2^20): integer atomics are order-independent -> deterministic
        unsigned long long q = (unsigned long long)(sm[0] * 1048576.0f + 0.5f);
        atomicAdd(lsum, q);
        __threadfence();
        int done = atomicAdd(ldone, 1);
        if (done == 4095) {              // last block finalizes the loss
            __threadfence();
            unsigned long long tot = *(volatile unsigned long long*)lsum;
            // loss = 1.25 * mean(diff^2) = 1.25 * (tot / 2^20) / 4194304
            out[0] = (float)((double)tot * (1.25 / (1048576.0 * 4194304.0)));
        }
    }
}

extern "C" void kernel_launch(void* const* d_in, const int* in_sizes, int n_in,
                              void* d_out, int out_size, void* d_ws, size_t ws_size,
                              hipStream_t stream) {
    const float* x = (const float*)d_in[0];   // [64,64,32,32]
    const float* e = (const float*)d_in[1];   // [1024,64]
    float* out = (float*)d_out;

    // ws: esq 4KB | Eh 128KB | El 128KB | idx 256KB | count 4KB | list 256KB | lsum/ldone 4KB
    char* wsb = (char*)d_ws;
    float*              esq   = (float*)wsb;
    unsigned short*     Eh    = (unsigned short*)(wsb + 4096);
    unsigned short*     El    = (unsigned short*)(wsb + 4096 + 131072);
    int*                idx   = (int*)(wsb + 4096 + 2 * 131072);
    int*                count = (int*)(wsb + 4096 + 2 * 131072 + NPIX * 4);
    int*                list  = (int*)(wsb + 4096 + 2 * 131072 + NPIX * 4 + 4096);
    unsigned long long* lsum  = (unsigned long long*)(wsb + 4096 + 2 * 131072 + 2 * NPIX * 4 + 4096);
    int*                ldone = (int*)((char*)lsum + 64);

    esplit_kernel<<<4, 256, 0, stream>>>(e, esq, Eh, El, count, lsum, ldone);
    gemm_kernel<<<NPIX / 64, 256, 0, stream>>>(x, Eh, El, esq, count, list, idx, out);
    cleanup_kernel<<<512, 256, 0, stream>>>(x, e, esq, count, list, idx, out);
    gather_kernel<<<4096, 256, 0, stream>>>(x, e, idx, out, lsum, ldone);
}

// Round 20
// 112.396 us; speedup vs baseline: 2.1256x; 2.1256x over previous
//
#include <hip/hip_runtime.h>

// VQ-VAE VectorQuantizer forward, fp32, MI355X.
// B=64, C=D=64, H=W=32 -> N=65536 pixels, K=1024 codes.
// Outputs (flat concat): [0] loss, [1..4194305) quantized BCHW, [4194305..) indices (as float)
//
// R20: revert R19's fused loss (per-block __threadfence = device-scope L2
// writeback on 8-XCD gfx950 -> gather serialized at 178us, VALUBusy 0.5%).
// Back to R18's proven gather(partials) + tiny loss kernel. KEEP R19 gemm
// (6-deep MFMA chain, 4-tile windows, median-tree top2 — field-validated
// correct at absmax 3.8e-6).
// MARGIN 8e-5 (R14-19 validated). Exact-path arithmetic BIT-IDENTICAL to
// R0-R19 (passed): pairwise-8 x_sq (contract off), d-ascending fp32 FMA
// chain, (xsq-2d)+esq, first-occurrence argmin.

#define KCODES 1024
#define DDIM   64
#define NPIX   65536
#define QELEMS 4194304
#define IDX_OFF (1 + QELEMS)
#define MARGIN 8e-5f
#define WT     4           // tiles per window
#define NWIN   16          // 64 tiles / 4
#define NB     8           // pixels per cleanup chunk

typedef __attribute__((ext_vector_type(8))) short bf16x8;
typedef __attribute__((ext_vector_type(4))) float f32x4;

static __device__ __forceinline__ unsigned short f2bf(float f) {
    unsigned int u = __float_as_uint(f);
    unsigned int r = (u + 0x7FFFu + ((u >> 16) & 1u)) >> 16;   // RNE
    return (unsigned short)r;
}
static __device__ __forceinline__ float bf2f(unsigned short h) {
    return __uint_as_float(((unsigned int)h) << 16);
}

// ---------------- e prep: esq (EXACT pairwise-8) + bf16 split of (-2e) ----------------
__global__ void __launch_bounds__(256) esplit_kernel(const float* __restrict__ e,
                                                     float* __restrict__ esq,
                                                     unsigned short* __restrict__ Eh,
                                                     unsigned short* __restrict__ El,
                                                     int* __restrict__ count) {
    if (blockIdx.x == 0 && threadIdx.x == 0) *count = 0;
    int k = blockIdx.x * 256 + threadIdx.x;
    if (k >= KCODES) return;
    const float* row = e + k * DDIM;
    {
#pragma clang fp contract(off)
        float r[8];
#pragma unroll
        for (int j = 0; j < 8; ++j) r[j] = row[j] * row[j];
#pragma unroll
        for (int i = 1; i < 8; ++i) {
#pragma unroll
            for (int j = 0; j < 8; ++j) { float v = row[i * 8 + j]; r[j] += v * v; }
        }
        esq[k] = ((r[0] + r[1]) + (r[2] + r[3])) + ((r[4] + r[5]) + (r[6] + r[7]));
    }
#pragma unroll
    for (int d = 0; d < DDIM; ++d) {
        float v = -2.0f * row[d];              // exact scaling
        unsigned short h = f2bf(v);
        Eh[k * DDIM + d] = h;
        El[k * DDIM + d] = f2bf(v - bf2f(h));
    }
}

// ---------------- MFMA approx scores + top-2 + fused compact (R19-validated) ----------------
// Block = 256 thr = 4 waves; 64 px/block. 4-tile windows, 16 barriers.
__global__ void __launch_bounds__(256, 4) gemm_kernel(const float* __restrict__ x,
                                                      const unsigned short* __restrict__ Eh,
                                                      const unsigned short* __restrict__ El,
                                                      const float* __restrict__ esq,
                                                      int* __restrict__ count,
                                                      int* __restrict__ list,
                                                      int* __restrict__ idx,
                                                      float* __restrict__ out) {
    __shared__ float x_lds[DDIM][64];              // 16KB
    __shared__ float esq_lds[KCODES];              // 4KB
    __shared__ unsigned char btile[2][WT][4096];   // 32KB dbuf window (per tile: Eh 2KB | El 2KB)
    __shared__ int sflag[64];

    const int tid = threadIdx.x;
    const int w = __builtin_amdgcn_readfirstlane(tid >> 6);
    const int l = tid & 63;
    const int g = l >> 4;              // 0..3
    const int col = l & 15;
    const int pxbase = blockIdx.x * 64;
    const int b = pxbase >> 10;
    const int p0 = pxbase & 1023;

    // stage x tile + esq
    {
        const float* xg = x + (size_t)b * 65536 + p0;
        for (int t = tid; t < DDIM * 64; t += 256)
            x_lds[t >> 6][t & 63] = xg[(size_t)(t >> 6) * 1024 + (t & 63)];
        for (int t = tid; t < KCODES; t += 256)
            esq_lds[t] = esq[t];
    }
    __syncthreads();

    // A fragments: row = col (px_local = w*16+col), k(d)-slot = g*8 + j (+32 per d-half)
    bf16x8 Ah0, Ah1, Al0, Al1;
    {
        const int pxl = w * 16 + col;
#pragma unroll
        for (int j = 0; j < 8; ++j) {
            float v0 = x_lds[g * 8 + j][pxl];
            unsigned short h0 = f2bf(v0);
            Ah0[j] = (short)h0;
            Al0[j] = (short)f2bf(v0 - bf2f(h0));
            float v1 = x_lds[32 + g * 8 + j][pxl];
            unsigned short h1 = f2bf(v1);
            Ah1[j] = (short)h1;
            Al1[j] = (short)f2bf(v1 - bf2f(h1));
        }
    }

    // B staging: thread covers 16B of each 4KB tile; 4 tiles per window.
    // swizzle: dchunk ^= (code&7)<<4 (bijective within each 128B code-row).
    const unsigned short* src_base = (tid < 128) ? Eh : El;
    const int u = tid & 127;
    const int code_w = u >> 3;
    const int dst_off = ((tid >> 7) << 11) + (code_w << 7)
                      + (((u & 7) << 4) ^ ((code_w & 7) << 4));
    float4 s0g, s1g, s2g, s3g;
    auto LDW = [&](int i) {    // load window i (tiles 4i..4i+3)
        const char* sb = (const char*)src_base + (size_t)(4 * i) * 2048 + (size_t)u * 16;
        s0g = *(const float4*)(sb);
        s1g = *(const float4*)(sb + 2048);
        s2g = *(const float4*)(sb + 4096);
        s3g = *(const float4*)(sb + 6144);
    };
    auto STW = [&](int i) {
        *(float4*)&btile[i & 1][0][dst_off] = s0g;
        *(float4*)&btile[i & 1][1][dst_off] = s1g;
        *(float4*)&btile[i & 1][2][dst_off] = s2g;
        *(float4*)&btile[i & 1][3][dst_off] = s3g;
    };

    const int cx = (col & 7) << 4;
    const int rb = col << 7;
    const int oh0 = rb + ((g << 4) ^ cx);
    const int oh1 = rb + (((g << 4) + 64) ^ cx);

    float m1_0 = 3.4e38f, m1_1 = 3.4e38f, m1_2 = 3.4e38f, m1_3 = 3.4e38f;
    float m2_0 = 3.4e38f, m2_1 = 3.4e38f, m2_2 = 3.4e38f, m2_3 = 3.4e38f;
    int i1_0 = 0, i1_1 = 0, i1_2 = 0, i1_3 = 0;

    LDW(0); STW(0);    // window 0 staged (vmcnt auto before ds_write)
    LDW(1);            // window 1 in flight
    __syncthreads();

#pragma unroll 1
    for (int wn = 0; wn < NWIN; ++wn) {
        if (wn + 1 < NWIN) STW(wn + 1);   // buf (wn+1)&1: read finished at last barrier
        if (wn + 2 < NWIN) LDW(wn + 2);

        const unsigned char* bw = &btile[wn & 1][0][0];
        const int kbase = wn * 64 + col;

        // 4 tiles, each a single 6-deep MFMA chain (3 split terms x 2 d-halves),
        // acc seeded with esq -> score = esq - 2*dot directly, zero VALU adds.
        f32x4 t0, t1, t2, t3;
#define CHAIN(J, ACC)                                                          \
        {                                                                      \
            const unsigned char* bp_ = bw + (J) * 4096;                        \
            const bf16x8 Bh0 = *(const bf16x8*)(bp_ + oh0);                    \
            const bf16x8 Bh1 = *(const bf16x8*)(bp_ + oh1);                    \
            const bf16x8 Bl0 = *(const bf16x8*)(bp_ + 2048 + oh0);             \
            const bf16x8 Bl1 = *(const bf16x8*)(bp_ + 2048 + oh1);             \
            const float qe_ = esq_lds[kbase + (J) * 16];                       \
            ACC = (f32x4){qe_, qe_, qe_, qe_};                                 \
            ACC = __builtin_amdgcn_mfma_f32_16x16x32_bf16(Ah0, Bh0, ACC, 0, 0, 0); \
            ACC = __builtin_amdgcn_mfma_f32_16x16x32_bf16(Al0, Bh0, ACC, 0, 0, 0); \
            ACC = __builtin_amdgcn_mfma_f32_16x16x32_bf16(Ah0, Bl0, ACC, 0, 0, 0); \
            ACC = __builtin_amdgcn_mfma_f32_16x16x32_bf16(Ah1, Bh1, ACC, 0, 0, 0); \
            ACC = __builtin_amdgcn_mfma_f32_16x16x32_bf16(Al1, Bh1, ACC, 0, 0, 0); \
            ACC = __builtin_amdgcn_mfma_f32_16x16x32_bf16(Ah1, Bl1, ACC, 0, 0, 0); \
        }
        CHAIN(0, t0)
        CHAIN(1, t1)
        CHAIN(2, t2)
        CHAIN(3, t3)
#undef CHAIN

        // 4-score median-tree top2 per pixel stream; ks ascending (kbase+16J);
        // all strict-< tie-breaks pick the lower k == first-occurrence.
#define WTOP(R, M1, M2, I1)                                                    \
        {                                                                      \
            float s0_ = t0[R], s1_ = t1[R], s2_ = t2[R], s3_ = t3[R];          \
            float p01 = fminf(s0_, s1_), q01 = fmaxf(s0_, s1_);                \
            float p23 = fminf(s2_, s3_), q23 = fmaxf(s2_, s3_);                \
            int i01 = (s1_ < s0_) ? kbase + 16 : kbase;                        \
            int i23 = (s3_ < s2_) ? kbase + 48 : kbase + 32;                   \
            float wmin = fminf(p01, p23);                                      \
            float wsec = fminf(fminf(q01, q23), fmaxf(p01, p23));              \
            int wi = (p23 < p01) ? i23 : i01;                                  \
            M2 = fminf(M2, fminf(wsec, fmaxf(M1, wmin)));                      \
            if (wmin < M1) I1 = wi;                                            \
            M1 = fminf(M1, wmin);                                              \
        }
        WTOP(0, m1_0, m2_0, i1_0)
        WTOP(1, m1_1, m2_1, i1_1)
        WTOP(2, m1_2, m2_2, i1_2)
        WTOP(3, m1_3, m2_3, i1_3)
#undef WTOP
        __syncthreads();
    }

    // cross-lane merge over the 16 lanes of group g; write idx/out + LDS flag
#define MERGE(M1, M2, I1, R)                                                   \
    {                                                                          \
        float a1_ = M1, a2_ = M2; int j1 = I1;                                 \
        _Pragma("unroll")                                                      \
        for (int off = 1; off < 16; off <<= 1) {                               \
            float b1 = __shfl_xor(a1_, off);                                   \
            int jb = __shfl_xor(j1, off);                                      \
            float b2 = __shfl_xor(a2_, off);                                   \
            float hi = fmaxf(a1_, b1);                                         \
            a2_ = fminf(fminf(a2_, b2), hi);                                   \
            if (b1 < a1_) j1 = jb;                                             \
            a1_ = fminf(a1_, b1);                                              \
        }                                                                      \
        if (col == 0) {                                                        \
            int pxl = w * 16 + g * 4 + (R);                                    \
            sflag[pxl] = (a2_ <= a1_ + MARGIN) ? 1 : 0;                        \
            int px = pxbase + pxl;                                             \
            idx[px] = j1;                                                      \
            out[IDX_OFF + px] = (float)j1;                                     \
        }                                                                      \
    }
    MERGE(m1_0, m2_0, i1_0, 0)
    MERGE(m1_1, m2_1, i1_1, 1)
    MERGE(m1_2, m2_2, i1_2, 2)
    MERGE(m1_3, m2_3, i1_3, 3)
#undef MERGE

    // fused compaction: wave 0 ballots the 64 flags, one atomicAdd
    __syncthreads();
    if (tid < 64) {
        const bool f = sflag[tid] != 0;
        unsigned long long m = __ballot(f);
        int base = 0;
        if (l == 0 && m) base = atomicAdd(count, __popcll(m));
        base = __shfl(base, 0);
        if (f) {
            unsigned long long below = m & ((1ULL << l) - 1ULL);
            list[base + __popcll(below)] = pxbase + tid;
        }
    }
}

// ---------------- cleanup (R17-19 validated): exact argmin, e tiled via LDS ----------------
__global__ void __launch_bounds__(256, 4) cleanup_kernel(const float* __restrict__ x,
                                                         const float* __restrict__ e,
                                                         const float* __restrict__ esq,
                                                         const int* __restrict__ count,
                                                         const int* __restrict__ list,
                                                         int* __restrict__ idx,
                                                         float* __restrict__ out) {
    __shared__ float tile[DDIM][257];   // 65.8KB transpose tile
    __shared__ float xs[NB][68];
    __shared__ float xsqs[NB];
    __shared__ float rbest[4];
    __shared__ int   ridx[4];
    __shared__ int   plist[NB];

    const int tid = threadIdx.x;
    const int cnt = *count;
    const int nchunk = (cnt + NB - 1) / NB;

    for (int chunk = blockIdx.x; chunk < nchunk; chunk += gridDim.x) {
        const int base = chunk * NB;
        const int np = min(NB, cnt - base);      // block-uniform

        if (tid < np) plist[tid] = list[base + tid];
        __syncthreads();
        for (int q = tid; q < np * 64; q += 256) {
            const int pp = q >> 6, d = q & 63;
            const int p = plist[pp];
            xs[pp][d] = x[(size_t)(p >> 10) * 65536 + (size_t)d * 1024 + (p & 1023)];
        }
        __syncthreads();
        if (tid < np) {
#pragma clang fp contract(off)
            float r[8];
#pragma unroll
            for (int j = 0; j < 8; ++j) { float v = xs[tid][j]; r[j] = v * v; }
#pragma unroll
            for (int ii = 1; ii < 8; ++ii) {
#pragma unroll
                for (int j = 0; j < 8; ++j) { float v = xs[tid][ii * 8 + j]; r[j] += v * v; }
            }
            xsqs[tid] = ((r[0] + r[1]) + (r[2] + r[3])) + ((r[4] + r[5]) + (r[6] + r[7]));
        }

        float best[NB];
        int bidx[NB];
#pragma unroll
        for (int pp = 0; pp < NB; ++pp) { best[pp] = 3.4e38f; bidx[pp] = 0; }

#pragma unroll 1
        for (int T = 0; T < 4; ++T) {
            __syncthreads();
#pragma unroll
            for (int i = 0; i < 16; ++i) {
                const float4 v = *(const float4*)(e + (size_t)T * 16384 + (size_t)i * 1024 + tid * 4);
                const int c = 16 * i + (tid >> 4);
                const int d0 = (4 * tid) & 63;
                tile[d0 + 0][c] = v.x;
                tile[d0 + 1][c] = v.y;
                tile[d0 + 2][c] = v.z;
                tile[d0 + 3][c] = v.w;
            }
            __syncthreads();
            const float qe = esq[T * 256 + tid];
            const int kk = T * 256 + tid;
#pragma unroll
            for (int pp = 0; pp < NB; ++pp) {
                if (pp < np) {
                    float dt = 0.f;
#pragma unroll
                    for (int d = 0; d < DDIM; ++d)
                        dt = __builtin_fmaf(xs[pp][d], tile[d][tid], dt);
                    const float s = (xsqs[pp] - 2.0f * dt) + qe;
                    if (s < best[pp]) { best[pp] = s; bidx[pp] = kk; }
                }
            }
        }

#pragma unroll
        for (int pp = 0; pp < NB; ++pp) {
            if (pp < np) {
                float bb = best[pp];
                int bj = bidx[pp];
#pragma unroll
                for (int off = 1; off < 64; off <<= 1) {
                    float b2 = __shfl_xor(bb, off);
                    int k2 = __shfl_xor(bj, off);
                    if (b2 < bb || (b2 == bb && k2 < bj)) { bb = b2; bj = k2; }
                }
                if ((tid & 63) == 0) { rbest[tid >> 6] = bb; ridx[tid >> 6] = bj; }
                __syncthreads();
                if (tid == 0) {
                    float b0 = rbest[0]; int j0 = ridx[0];
#pragma unroll
                    for (int c2 = 1; c2 < 4; ++c2)
                        if (rbest[c2] < b0 || (rbest[c2] == b0 && ridx[c2] < j0)) {
                            b0 = rbest[c2]; j0 = ridx[c2];
                        }
                    const int p = plist[pp];
                    idx[p] = j0;
                    out[IDX_OFF + p] = (float)j0;
                }
                __syncthreads();
            }
        }
        __syncthreads();
    }
}

// ---------------- gather + transpose + per-block loss partials (R18-proven) ----------------
__global__ void __launch_bounds__(256) gather_kernel(const float* __restrict__ x,
                                                     const float* __restrict__ e,
                                                     const int* __restrict__ idx,
                                                     float* __restrict__ out,
                                                     float* __restrict__ partial) {
    const int bd = blockIdx.x;          // = b*64 + d
    const int b = bd >> 6;
    const int d = bd & 63;
    const size_t base = (size_t)bd * 1024;
    const int* idxb = idx + b * 1024;

    float acc = 0.f;
#pragma unroll
    for (int j = 0; j < 4; ++j) {
        int p = threadIdx.x + j * 256;
        int k = idxb[p];
        float ev = e[k * 64 + d];
        float xv = x[base + p];
        out[1 + base + p] = ev;         // quantized (straight-through == codebook value)
        float df = ev - xv;
        acc = __builtin_fmaf(df, df, acc);
    }
    __shared__ float sm[256];
    sm[threadIdx.x] = acc;
    __syncthreads();
    for (int s = 128; s > 0; s >>= 1) {
        if (threadIdx.x < s) sm[threadIdx.x] += sm[threadIdx.x + s];
        __syncthreads();
    }
    if (threadIdx.x == 0) partial[bd] = sm[0];
}

// ---------------- deterministic loss finalize ----------------
__global__ void __launch_bounds__(256) loss_kernel(const float* __restrict__ partial,
                                                   float* __restrict__ out) {
    float acc = 0.f;
    for (int i = threadIdx.x; i < 4096; i += 256) acc += partial[i];
    __shared__ float sm[256];
    sm[threadIdx.x] = acc;
    __syncthreads();
    for (int s = 128; s > 0; s >>= 1) {
        if (threadIdx.x < s) sm[threadIdx.x] += sm[threadIdx.x + s];
        __syncthreads();
    }
    // loss = q_latent + 0.25*e_latent = 1.25 * mean(diff^2)
    if (threadIdx.x == 0) out[0] = sm[0] * (1.25f / 4194304.f);
}

extern "C" void kernel_launch(void* const* d_in, const int* in_sizes, int n_in,
                              void* d_out, int out_size, void* d_ws, size_t ws_size,
                              hipStream_t stream) {
    const float* x = (const float*)d_in[0];   // [64,64,32,32]
    const float* e = (const float*)d_in[1];   // [1024,64]
    float* out = (float*)d_out;

    // ws: esq 4KB | Eh 128KB | El 128KB | idx 256KB | count 4KB | list 256KB | partial 16KB
    char* wsb = (char*)d_ws;
    float*          esq     = (float*)wsb;
    unsigned short* Eh      = (unsigned short*)(wsb + 4096);
    unsigned short* El      = (unsigned short*)(wsb + 4096 + 131072);
    int*            idx     = (int*)(wsb + 4096 + 2 * 131072);
    int*            count   = (int*)(wsb + 4096 + 2 * 131072 + NPIX * 4);
    int*            list    = (int*)(wsb + 4096 + 2 * 131072 + NPIX * 4 + 4096);
    float*          partial = (float*)(wsb + 4096 + 2 * 131072 + 2 * NPIX * 4 + 4096);

    esplit_kernel<<<4, 256, 0, stream>>>(e, esq, Eh, El, count);
    gemm_kernel<<<NPIX / 64, 256, 0, stream>>>(x, Eh, El, esq, count, list, idx, out);
    cleanup_kernel<<<512, 256, 0, stream>>>(x, e, esq, count, list, idx, out);
    gather_kernel<<<4096, 256, 0, stream>>>(x, e, idx, out, partial);
    loss_kernel<<<1, 256, 0, stream>>>(partial, out);
}